// Round 1
// baseline (368.511 us; speedup 1.0000x reference)
//
#include <hip/hip_runtime.h>

#define MAXD 192
#define NCH  16

// Bilinear sample, align_corners pixel coords already, padding_mode='zeros'.
__device__ __forceinline__ float bsample(const float* __restrict__ img, float x, float y,
                                         int H, int W) {
    float xf = floorf(x), yf = floorf(y);
    int x0 = (int)xf, y0 = (int)yf;
    float wx = x - xf, wy = y - yf;
    int x1 = x0 + 1, y1 = y0 + 1;
    bool xv0 = (x0 >= 0) && (x0 < W);
    bool xv1 = (x1 >= 0) && (x1 < W);
    bool yv0 = (y0 >= 0) && (y0 < H);
    bool yv1 = (y1 >= 0) && (y1 < H);
    float v00 = (xv0 && yv0) ? img[y0 * W + x0] : 0.0f;
    float v01 = (xv1 && yv0) ? img[y0 * W + x1] : 0.0f;
    float v10 = (xv0 && yv1) ? img[y1 * W + x0] : 0.0f;
    float v11 = (xv1 && yv1) ? img[y1 * W + x1] : 0.0f;
    float top = v00 + wx * (v01 - v00);
    float bot = v10 + wx * (v11 - v10);
    return top + wy * (bot - top);
}

// One block per (point n, output level j in 0..7).
// pass 0: level j+8 (scale 4, D=48); pass 1: level j (scale 1, D=192).
__global__ __launch_bounds__(256) void pbm_kernel(
    const float* __restrict__ lfeat,   // (L, 1, C, H, W)
    const float* __restrict__ rfeat,   // (L, 1, C, H, W)
    const float* __restrict__ points,  // (1, N, 2)
    const int* __restrict__ pW, const int* __restrict__ pH,
    float* __restrict__ out)           // (1, N, 192, 8)
{
    const int W = *pW, H = *pH;
    const int n   = blockIdx.x;
    const int j   = blockIdx.y;
    const int tid = threadIdx.x;
    const float px = points[2 * n];
    const float py = points[2 * n + 1];

    __shared__ float sv[5][200];        // one channel's right row-strip samples
    __shared__ float slf[5][5];         // one channel's left window
    __shared__ float val4[MAXD / 4];    // scale-4 costs (D=48)
    __shared__ float val1[MAXD];        // scale-1 costs (D=192)

#pragma unroll
    for (int pass = 0; pass < 2; ++pass) {
        const int s  = (pass == 0) ? 4 : 1;
        const int D  = MAXD / s;        // 48 or 192
        const int KN = D + 4;           // right strip width (in units of s)
        const int lvl = (pass == 0) ? (j + 8) : j;
        const float* Lb = lfeat + (size_t)lvl * NCH * H * W;
        const float* Rb = rfeat + (size_t)lvl * NCH * H * W;

        float acc = 0.0f;
        for (int c = 0; c < NCH; ++c) {
            const float* Lc = Lb + (size_t)c * H * W;
            const float* Rc = Rb + (size_t)c * H * W;

            // Stage right strip: x = px + s*(kk - (D+1)), y = py + s*(yy-2)
            for (int t = tid; t < 5 * KN; t += 256) {
                int yy = t / KN;
                int kk = t - yy * KN;
                float x = px + (float)(s * (kk - (D + 1)));
                float y = py + (float)(s * (yy - 2));
                sv[yy][kk] = bsample(Rc, x, y, H, W);
            }
            // Stage left 5x5 window
            if (tid < 25) {
                int yy = tid / 5, xx = tid - yy * 5;
                slf[yy][xx] = bsample(Lc, px + (float)(s * (xx - 2)),
                                          py + (float)(s * (yy - 2)), H, W);
            }
            __syncthreads();

            // Each thread i < D accumulates |lf - rf| over the 5x5 window.
            // rf index: kk = xx + (D-1) - i  (consecutive lanes -> consecutive addrs)
            if (tid < D) {
                int base = D - 1 - tid;
#pragma unroll
                for (int yy = 0; yy < 5; ++yy) {
#pragma unroll
                    for (int xx = 0; xx < 5; ++xx)
                        acc += fabsf(slf[yy][xx] - sv[yy][base + xx]);
                }
            }
            __syncthreads();
        }

        if (tid < D) {
            float cost = acc * (1.0f / (NCH * 25.0f));
            float v = 1.0f - expf(-cost);
            if (pass == 0) val4[tid] = v;
            else           val1[tid] = v;
        }
        __syncthreads();
    }

    // Combine: out[n][d][j] = val1[d] + upsample48->192(val4)[d]
    if (tid < MAXD) {
        float pos = (float)tid * (47.0f / 191.0f);
        float i0f = floorf(pos);
        int   i0  = (int)i0f;
        float w   = pos - i0f;
        int   i1  = min(i0 + 1, 47);
        float up  = val4[i0] + w * (val4[i1] - val4[i0]);
        out[((size_t)n * MAXD + tid) * 8 + j] = val1[tid] + up;
    }
}

extern "C" void kernel_launch(void* const* d_in, const int* in_sizes, int n_in,
                              void* d_out, int out_size, void* d_ws, size_t ws_size,
                              hipStream_t stream) {
    const float* lf  = (const float*)d_in[0];
    const float* rf  = (const float*)d_in[1];
    const float* pts = (const float*)d_in[2];
    const int*   pW  = (const int*)d_in[3];
    const int*   pH  = (const int*)d_in[4];
    float* out = (float*)d_out;

    const int N = in_sizes[2] / 2;   // (B=1, N, 2)
    dim3 grid(N, 8, 1);
    pbm_kernel<<<grid, 256, 0, stream>>>(lf, rf, pts, pW, pH, out);
}